// Round 1
// baseline (507.542 us; speedup 1.0000x reference)
//
#include <hip/hip_runtime.h>
#include <hip/hip_bf16.h>
#include <math.h>

typedef __bf16 bf16_t;
typedef __bf16 bf16x8 __attribute__((ext_vector_type(8)));
typedef float  f32x4  __attribute__((ext_vector_type(4)));

#define D_MODEL 1024
#define NH      16
#define HD      64
#define BATCH   2
#define SEQ     2048
#define MROWS   (BATCH*SEQ)   // 4096
#define QKVN    (3*D_MODEL)   // 3072

// ---------------- fp32 -> bf16 convert (4 elems/thread) ----------------
__global__ void cvt_f32_bf16(const float* __restrict__ s, bf16_t* __restrict__ d, int n) {
    int i = (blockIdx.x * blockDim.x + threadIdx.x) * 4;
    if (i < n) {
        float4 v = *(const float4*)(s + i);
        d[i]   = (bf16_t)v.x;
        d[i+1] = (bf16_t)v.y;
        d[i+2] = (bf16_t)v.z;
        d[i+3] = (bf16_t)v.w;
    }
}

// ---------------- NT GEMM: C[M,N] = A[M,K] * B[N,K]^T  (bf16 in, OutT out) ----
// block = 256 thr = 4 waves in 2x2; each wave computes 64x64 via 4x4 MFMA tiles.
// Fragment layouts (HW-verified gfx950):
//   A frag: A[m=lane&15][k=(lane>>4)*8+j]  -> contiguous bf16x8 from row-major A
//   B frag: B'[k][n]=B[n][k]               -> contiguous bf16x8 from row-major B
//   C/D:    col=lane&15, row=(lane>>4)*4+reg
template <typename OutT>
__global__ __launch_bounds__(256) void gemm_nt(const bf16_t* __restrict__ A,
                                               const bf16_t* __restrict__ Bm,
                                               OutT* __restrict__ C,
                                               int M, int N, int K) {
    const int w    = threadIdx.x >> 6;
    const int lane = threadIdx.x & 63;
    const int quad = lane >> 4;
    const int l16  = lane & 15;
    const int m0   = blockIdx.x * 128 + (w >> 1) * 64;
    const int n0   = blockIdx.y * 128 + (w & 1) * 64;

    f32x4 acc[4][4];
    #pragma unroll
    for (int i = 0; i < 4; i++)
        #pragma unroll
        for (int j = 0; j < 4; j++)
            acc[i][j] = (f32x4){0.f, 0.f, 0.f, 0.f};

    const bf16_t* Ap = A  + (size_t)(m0 + l16) * K + quad * 8;
    const bf16_t* Bp = Bm + (size_t)(n0 + l16) * K + quad * 8;

    for (int k = 0; k < K; k += 32) {
        bf16x8 af[4], bfr[4];
        #pragma unroll
        for (int mi = 0; mi < 4; mi++)
            af[mi] = *(const bf16x8*)(Ap + (size_t)mi * 16 * K + k);
        #pragma unroll
        for (int ni = 0; ni < 4; ni++)
            bfr[ni] = *(const bf16x8*)(Bp + (size_t)ni * 16 * K + k);
        #pragma unroll
        for (int mi = 0; mi < 4; mi++)
            #pragma unroll
            for (int ni = 0; ni < 4; ni++)
                acc[mi][ni] = __builtin_amdgcn_mfma_f32_16x16x32_bf16(
                    af[mi], bfr[ni], acc[mi][ni], 0, 0, 0);
    }

    #pragma unroll
    for (int mi = 0; mi < 4; mi++)
        #pragma unroll
        for (int ni = 0; ni < 4; ni++) {
            const int col = n0 + ni * 16 + l16;
            #pragma unroll
            for (int r = 0; r < 4; r++) {
                const int row = m0 + mi * 16 + quad * 4 + r;
                C[(size_t)row * N + col] = (OutT)acc[mi][ni][r];
            }
        }
}

// ---------------- RoPE + head split + V transpose ----------------
// qkv: [B*S, 3072] bf16. Writes Q,K: [bh][s][d] (rope'd), VT: [bh][d][s].
// thread t -> (b, h, d2, s) with s innermost (coalesced VT writes).
__global__ void rope_split(const bf16_t* __restrict__ qkv,
                           const int* __restrict__ pos,
                           bf16_t* __restrict__ Qh,
                           bf16_t* __restrict__ Kh,
                           bf16_t* __restrict__ VT) {
    int t  = blockIdx.x * blockDim.x + threadIdx.x;  // B*NH*32*S = 2,097,152
    int s  = t & (SEQ - 1);
    int d2 = (t >> 11) & 31;
    int h  = (t >> 16) & 15;
    int b  = t >> 20;
    int bh = b * NH + h;

    const bf16_t* row = qkv + (size_t)(b * SEQ + s) * QKVN;
    float qe = (float)row[h * HD + 2 * d2];
    float qo = (float)row[h * HD + 2 * d2 + 1];
    float ke = (float)row[D_MODEL + h * HD + 2 * d2];
    float ko = (float)row[D_MODEL + h * HD + 2 * d2 + 1];
    float ve = (float)row[2 * D_MODEL + h * HD + 2 * d2];
    float vo = (float)row[2 * D_MODEL + h * HD + 2 * d2 + 1];

    float p   = (float)pos[s];
    // theta^(-2*d2/64) = exp(-d2 * ln(10000)/32)
    float inv = __expf(-0.28782313662425575f * (float)d2);
    float f   = p * inv;
    float c   = cosf(f);
    float sn  = sinf(f);

    size_t qb = ((size_t)bh * SEQ + s) * HD + 2 * d2;
    Qh[qb]     = (bf16_t)(qe * c - qo * sn);
    Qh[qb + 1] = (bf16_t)(qo * c + qe * sn);
    Kh[qb]     = (bf16_t)(ke * c - ko * sn);
    Kh[qb + 1] = (bf16_t)(ko * c + ke * sn);

    size_t vb = ((size_t)bh * HD + 2 * d2) * SEQ + s;
    VT[vb]       = (bf16_t)ve;
    VT[vb + SEQ] = (bf16_t)vo;
}

// ---------------- causal flash attention ----------------
// grid: (S/64, B*NH); block 256 = 4 waves, each wave owns 16 Q rows.
// Per-lane online-softmax state is float4 (reg r <-> Q row quad*4+r).
__global__ __launch_bounds__(256) void flash_attn(const bf16_t* __restrict__ Qh,
                                                  const bf16_t* __restrict__ Kh,
                                                  const bf16_t* __restrict__ VT,
                                                  bf16_t* __restrict__ AO) {
    __shared__ __align__(16) bf16_t p_lds[4][16][72];  // per-wave P buffer, stride 72 (2-way bank alias = free)
    const int w    = threadIdx.x >> 6;
    const int lane = threadIdx.x & 63;
    const int quad = lane >> 4;
    const int l16  = lane & 15;
    const int qt   = (int)gridDim.x - 1 - (int)blockIdx.x;  // big blocks first
    const int bh   = blockIdx.y;

    const bf16_t* Qb = Qh + (size_t)bh * SEQ * HD;
    const bf16_t* Kb = Kh + (size_t)bh * SEQ * HD;
    const bf16_t* Vb = VT + (size_t)bh * HD * SEQ;

    const int q0 = qt * 64 + w * 16;

    bf16x8 aq0 = *(const bf16x8*)(Qb + (size_t)(q0 + l16) * HD + quad * 8);
    bf16x8 aq1 = *(const bf16x8*)(Qb + (size_t)(q0 + l16) * HD + 32 + quad * 8);

    f32x4 o[4];
    #pragma unroll
    for (int i = 0; i < 4; i++) o[i] = (f32x4){0.f, 0.f, 0.f, 0.f};
    f32x4 m_i = (f32x4){-1e30f, -1e30f, -1e30f, -1e30f};
    f32x4 l_i = (f32x4){0.f, 0.f, 0.f, 0.f};

    for (int kt = 0; kt <= qt; ++kt) {
        const int k0 = kt * 64;
        f32x4 sc[4];
        #pragma unroll
        for (int ni = 0; ni < 4; ni++) {
            bf16x8 kb0 = *(const bf16x8*)(Kb + (size_t)(k0 + ni * 16 + l16) * HD + quad * 8);
            bf16x8 kb1 = *(const bf16x8*)(Kb + (size_t)(k0 + ni * 16 + l16) * HD + 32 + quad * 8);
            f32x4 t = (f32x4){0.f, 0.f, 0.f, 0.f};
            t = __builtin_amdgcn_mfma_f32_16x16x32_bf16(aq0, kb0, t, 0, 0, 0);
            t = __builtin_amdgcn_mfma_f32_16x16x32_bf16(aq1, kb1, t, 0, 0, 0);
            sc[ni] = t * 0.125f;  // HEAD_DIM^-0.5
        }

        if (kt == qt) {  // diagonal tile: causal mask
            #pragma unroll
            for (int ni = 0; ni < 4; ni++) {
                const int kj = k0 + ni * 16 + l16;
                #pragma unroll
                for (int r = 0; r < 4; r++)
                    if (kj > q0 + quad * 4 + r) sc[ni][r] = -1e30f;
            }
        }

        // row max (all 16 rows of this wave at once: 4 regs x 16-lane butterfly)
        f32x4 vm;
        #pragma unroll
        for (int r = 0; r < 4; r++)
            vm[r] = fmaxf(fmaxf(sc[0][r], sc[1][r]), fmaxf(sc[2][r], sc[3][r]));
        #pragma unroll
        for (int d = 1; d < 16; d <<= 1) {
            #pragma unroll
            for (int r = 0; r < 4; r++)
                vm[r] = fmaxf(vm[r], __shfl_xor(vm[r], d));
        }

        f32x4 mnew, alpha;
        #pragma unroll
        for (int r = 0; r < 4; r++) {
            mnew[r]  = fmaxf(m_i[r], vm[r]);
            alpha[r] = __expf(m_i[r] - mnew[r]);
        }

        f32x4 rs = (f32x4){0.f, 0.f, 0.f, 0.f};
        #pragma unroll
        for (int ni = 0; ni < 4; ni++) {
            #pragma unroll
            for (int r = 0; r < 4; r++) {
                float pv = __expf(sc[ni][r] - mnew[r]);
                rs[r] += pv;
                p_lds[w][quad * 4 + r][ni * 16 + l16] = (bf16_t)pv;  // C-layout -> LDS
            }
        }
        #pragma unroll
        for (int d = 1; d < 16; d <<= 1) {
            #pragma unroll
            for (int r = 0; r < 4; r++)
                rs[r] += __shfl_xor(rs[r], d);
        }

        #pragma unroll
        for (int r = 0; r < 4; r++) l_i[r] = l_i[r] * alpha[r] + rs[r];
        m_i = mnew;
        #pragma unroll
        for (int ni = 0; ni < 4; ni++) o[ni] = o[ni] * alpha;

        // PV: read P back in A-layout (wave-private LDS, no barrier needed)
        #pragma unroll
        for (int ks = 0; ks < 2; ks++) {
            bf16x8 ap = *(const bf16x8*)(&p_lds[w][l16][ks * 32 + quad * 8]);
            #pragma unroll
            for (int ni = 0; ni < 4; ni++) {
                bf16x8 vb = *(const bf16x8*)(Vb + (size_t)(ni * 16 + l16) * SEQ + k0 + ks * 32 + quad * 8);
                o[ni] = __builtin_amdgcn_mfma_f32_16x16x32_bf16(ap, vb, o[ni], 0, 0, 0);
            }
        }
    }

    const int b = bh >> 4, h = bh & 15;
    #pragma unroll
    for (int ni = 0; ni < 4; ni++) {
        #pragma unroll
        for (int r = 0; r < 4; r++) {
            const size_t row = (size_t)b * SEQ + q0 + quad * 4 + r;
            AO[row * D_MODEL + h * HD + ni * 16 + l16] = (bf16_t)(o[ni][r] / l_i[r]);
        }
    }
}

// ---------------- launcher ----------------
extern "C" void kernel_launch(void* const* d_in, const int* in_sizes, int n_in,
                              void* d_out, int out_size, void* d_ws, size_t ws_size,
                              hipStream_t stream) {
    const float* x     = (const float*)d_in[0];
    const float* w_qkv = (const float*)d_in[1];
    const float* w_o   = (const float*)d_in[2];
    const int*   tpos  = (const int*)d_in[3];
    float*       out   = (float*)d_out;

    char* ws = (char*)d_ws;
    bf16_t* xb  = (bf16_t*)(ws);                 //  8 MB: x bf16        [4096,1024]
    bf16_t* wqb = (bf16_t*)(ws + 8388608);       //  6 MB: w_qkv bf16    [3072,1024]
    bf16_t* wob = (bf16_t*)(ws + 14680064);      //  2 MB: w_o bf16      [1024,1024]
    bf16_t* qkv = (bf16_t*)(ws + 16777216);      // 24 MB: qkv           [4096,3072]
    bf16_t* Qh  = (bf16_t*)(ws + 41943040);      //  8 MB: Q heads rope  [32,2048,64]
    bf16_t* Kh  = (bf16_t*)(ws + 50331648);      //  8 MB: K heads rope  [32,2048,64]
    bf16_t* VT  = (bf16_t*)(ws + 58720256);      //  8 MB: V^T           [32,64,2048]
    bf16_t* AO  = (bf16_t*)(ws + 67108864);      //  8 MB: attn out      [4096,1024]

    const int nx = MROWS * D_MODEL;      // 4,194,304
    const int nq = QKVN * D_MODEL;       // 3,145,728
    const int no = D_MODEL * D_MODEL;    // 1,048,576

    cvt_f32_bf16<<<nx / 1024, 256, 0, stream>>>(x, xb, nx);
    cvt_f32_bf16<<<nq / 1024, 256, 0, stream>>>(w_qkv, wqb, nq);
    cvt_f32_bf16<<<no / 1024, 256, 0, stream>>>(w_o, wob, no);

    // qkv = x @ w_qkv^T : M=4096, N=3072, K=1024
    gemm_nt<bf16_t><<<dim3(32, 24), 256, 0, stream>>>(xb, wqb, qkv, MROWS, QKVN, D_MODEL);

    rope_split<<<(BATCH * NH * 32 * SEQ) / 256, 256, 0, stream>>>(qkv, tpos, Qh, Kh, VT);

    flash_attn<<<dim3(SEQ / 64, BATCH * NH), 256, 0, stream>>>(Qh, Kh, VT, AO);

    // out = AO @ w_o^T : M=4096, N=1024, K=1024 (fp32 out)
    gemm_nt<float><<<dim3(32, 8), 256, 0, stream>>>(AO, wob, out, MROWS, D_MODEL, D_MODEL);
}

// Round 2
// 249.714 us; speedup vs baseline: 2.0325x; 2.0325x over previous
//
#include <hip/hip_runtime.h>
#include <hip/hip_bf16.h>
#include <math.h>

typedef __bf16 bf16_t;
typedef __bf16 bf16x8 __attribute__((ext_vector_type(8)));
typedef float  f32x4  __attribute__((ext_vector_type(4)));

#define D_MODEL 1024
#define NH      16
#define HD      64
#define BATCH   2
#define SEQ     2048
#define MROWS   (BATCH*SEQ)   // 4096
#define QKVN    (3*D_MODEL)   // 3072
#define FA_PAD  72            // LDS row stride (64 + 8): frag reads 2-way (free)

__device__ __forceinline__ void async_cp16(const bf16_t* g, bf16_t* l) {
    __builtin_amdgcn_global_load_lds(
        (const __attribute__((address_space(1))) void*)g,
        (__attribute__((address_space(3))) void*)l,
        16, 0, 0);
}

// ---------------- fp32 -> bf16 convert (4 elems/thread) ----------------
__global__ void cvt_f32_bf16(const float* __restrict__ s, bf16_t* __restrict__ d, int n) {
    int i = (blockIdx.x * blockDim.x + threadIdx.x) * 4;
    if (i < n) {
        float4 v = *(const float4*)(s + i);
        d[i]   = (bf16_t)v.x;
        d[i+1] = (bf16_t)v.y;
        d[i+2] = (bf16_t)v.z;
        d[i+3] = (bf16_t)v.w;
    }
}

// ---------------- NT GEMM (m97 recipe): C[M,N] = A[M,K] * B[N,K]^T ----------
// 128x128 block tile, BK=32, global_load_lds width-16 staging, 2-barrier K-loop.
template <typename OutT>
__global__ __launch_bounds__(256) void gemm_nt(const bf16_t* __restrict__ A,
                                               const bf16_t* __restrict__ Bm,
                                               OutT* __restrict__ C,
                                               int M, int N, int K) {
    __shared__ __align__(16) bf16_t As[128 * 32];   // 8 KB, [m][k]
    __shared__ __align__(16) bf16_t Bs[128 * 32];   // 8 KB, [n][k]
    const int tid  = threadIdx.x;
    const int w    = tid >> 6;
    const int lane = tid & 63;
    const int quad = lane >> 4;
    const int l16  = lane & 15;
    const int m0   = blockIdx.x * 128;
    const int n0   = blockIdx.y * 128;
    const int wm   = (w >> 1) * 64;
    const int wn   = (w & 1) * 64;

    f32x4 acc[4][4];
    #pragma unroll
    for (int i = 0; i < 4; i++)
        #pragma unroll
        for (int j = 0; j < 4; j++)
            acc[i][j] = (f32x4){0.f, 0.f, 0.f, 0.f};

    // staging granule g = tid (+256): row = g>>2, kcol = (g&3)*8
    const bf16_t* Ag0 = A  + (size_t)(m0 + (tid >> 2)) * K + (tid & 3) * 8;
    const bf16_t* Ag1 = Ag0 + (size_t)64 * K;
    const bf16_t* Bg0 = Bm + (size_t)(n0 + (tid >> 2)) * K + (tid & 3) * 8;
    const bf16_t* Bg1 = Bg0 + (size_t)64 * K;
    bf16_t* Al0 = &As[(size_t)tid * 8];
    bf16_t* Al1 = &As[((size_t)tid + 256) * 8];
    bf16_t* Bl0 = &Bs[(size_t)tid * 8];
    bf16_t* Bl1 = &Bs[((size_t)tid + 256) * 8];

    for (int k0 = 0; k0 < K; k0 += 32) {
        async_cp16(Ag0 + k0, Al0);
        async_cp16(Ag1 + k0, Al1);
        async_cp16(Bg0 + k0, Bl0);
        async_cp16(Bg1 + k0, Bl1);
        __syncthreads();   // drains vmcnt: DMA complete + all waves arrived

        bf16x8 af[4], bfr[4];
        #pragma unroll
        for (int mi = 0; mi < 4; mi++)
            af[mi] = *(const bf16x8*)&As[(wm + mi * 16 + l16) * 32 + quad * 8];
        #pragma unroll
        for (int ni = 0; ni < 4; ni++)
            bfr[ni] = *(const bf16x8*)&Bs[(wn + ni * 16 + l16) * 32 + quad * 8];
        #pragma unroll
        for (int mi = 0; mi < 4; mi++)
            #pragma unroll
            for (int ni = 0; ni < 4; ni++)
                acc[mi][ni] = __builtin_amdgcn_mfma_f32_16x16x32_bf16(
                    af[mi], bfr[ni], acc[mi][ni], 0, 0, 0);
        __syncthreads();   // readers done before next DMA overwrites
    }

    #pragma unroll
    for (int mi = 0; mi < 4; mi++)
        #pragma unroll
        for (int ni = 0; ni < 4; ni++) {
            const int col = n0 + wn + ni * 16 + l16;
            #pragma unroll
            for (int r = 0; r < 4; r++) {
                const int row = m0 + wm + mi * 16 + quad * 4 + r;
                C[(size_t)row * N + col] = (OutT)acc[mi][ni][r];
            }
        }
}

// ---------------- RoPE + head split + V transpose (coalesced) ----------------
// grid (SEQ/128, B*NH), block 256. Thread t: s_loc = t>>1 (0..127), half = t&1.
// Reads 64 B of Q/K/V per thread (contiguous); Q/K rope'd + written coalesced;
// V transposed through LDS -> VT [bh][d][s].
__global__ __launch_bounds__(256) void rope_split(const bf16_t* __restrict__ qkv,
                                                  const int* __restrict__ pos,
                                                  bf16_t* __restrict__ Qh,
                                                  bf16_t* __restrict__ Kh,
                                                  bf16_t* __restrict__ VT) {
    __shared__ bf16_t vs[128][FA_PAD];   // 18.4 KB
    const int tid   = threadIdx.x;
    const int s_loc = tid >> 1;
    const int half  = tid & 1;
    const int s0    = blockIdx.x * 128;
    const int bh    = blockIdx.y;
    const int b     = bh >> 4, h = bh & 15;
    const int s     = s0 + s_loc;

    const bf16_t* row = qkv + (size_t)(b * SEQ + s) * QKVN + h * HD + half * 32;

    bf16_t qbuf[32], kbuf[32], vbuf[32];
    #pragma unroll
    for (int j = 0; j < 4; j++) {
        *(bf16x8*)&qbuf[j * 8] = *(const bf16x8*)(row + j * 8);
        *(bf16x8*)&kbuf[j * 8] = *(const bf16x8*)(row + D_MODEL + j * 8);
        *(bf16x8*)&vbuf[j * 8] = *(const bf16x8*)(row + 2 * D_MODEL + j * 8);
    }

    const float pf = (float)pos[s];
    #pragma unroll
    for (int p = 0; p < 16; p++) {
        const int d2 = half * 16 + p;
        const float inv = __expf(-0.28782313662425575f * (float)d2);  // theta^(-d2/32)
        const float f = pf * inv;
        const float c = cosf(f), sn = sinf(f);
        float qe = (float)qbuf[2 * p], qo = (float)qbuf[2 * p + 1];
        float ke = (float)kbuf[2 * p], ko = (float)kbuf[2 * p + 1];
        qbuf[2 * p]     = (bf16_t)(qe * c - qo * sn);
        qbuf[2 * p + 1] = (bf16_t)(qo * c + qe * sn);
        kbuf[2 * p]     = (bf16_t)(ke * c - ko * sn);
        kbuf[2 * p + 1] = (bf16_t)(ko * c + ke * sn);
    }

    bf16_t* qdst = Qh + ((size_t)bh * SEQ + s) * HD + half * 32;
    bf16_t* kdst = Kh + ((size_t)bh * SEQ + s) * HD + half * 32;
    #pragma unroll
    for (int j = 0; j < 4; j++) {
        *(bf16x8*)(qdst + j * 8) = *(bf16x8*)&qbuf[j * 8];
        *(bf16x8*)(kdst + j * 8) = *(bf16x8*)&kbuf[j * 8];
        *(bf16x8*)&vs[s_loc][half * 32 + j * 8] = *(bf16x8*)&vbuf[j * 8];
    }
    __syncthreads();

    // V transpose out: thread t -> d = t>>2, s-chunk (t&3)*32
    const int d  = tid >> 2;
    const int sc = tid & 3;
    bf16_t tmp[32];
    #pragma unroll
    for (int i = 0; i < 32; i++) tmp[i] = vs[sc * 32 + i][d];
    bf16_t* vdst = VT + ((size_t)bh * HD + d) * SEQ + s0 + sc * 32;
    #pragma unroll
    for (int j = 0; j < 4; j++)
        *(bf16x8*)(vdst + j * 8) = *(bf16x8*)&tmp[j * 8];
}

// ---------------- causal flash attention (LDS-staged K/V, reg prefetch) -----
// 1024 blocks linear: xcd = bid&7, bh = (bid>>8)*8 + xcd, qt = 31-((bid>>3)&31).
// 4 waves, each owns 16 Q rows of a 64-row q-tile; K/V tiles staged in LDS.
__global__ __launch_bounds__(256) void flash_attn(const bf16_t* __restrict__ Qh,
                                                  const bf16_t* __restrict__ Kh,
                                                  const bf16_t* __restrict__ VT,
                                                  bf16_t* __restrict__ AO) {
    __shared__ __align__(16) bf16_t Ks[64 * FA_PAD];        // 9 KB  [kv][d]
    __shared__ __align__(16) bf16_t Vs[64 * FA_PAD];        // 9 KB  [d][kv]
    __shared__ __align__(16) bf16_t p_lds[4][16][FA_PAD];   // 9 KB  per-wave P

    const int tid  = threadIdx.x;
    const int w    = tid >> 6;
    const int lane = tid & 63;
    const int quad = lane >> 4;
    const int l16  = lane & 15;

    const int bid = blockIdx.x;
    const int xcd = bid & 7;
    const int mm  = bid >> 3;
    const int bh  = (mm >> 5) * 8 + xcd;      // same-bh blocks share an XCD (L2 locality)
    const int qt  = 31 - (mm & 31);           // big q-tiles dispatch first

    const bf16_t* Qb = Qh + (size_t)bh * SEQ * HD;
    const bf16_t* Kb = Kh + (size_t)bh * SEQ * HD;
    const bf16_t* Vb = VT + (size_t)bh * HD * SEQ;

    const int q0 = qt * 64 + w * 16;
    const bf16x8 aq0 = *(const bf16x8*)(Qb + (size_t)(q0 + l16) * HD + quad * 8);
    const bf16x8 aq1 = *(const bf16x8*)(Qb + (size_t)(q0 + l16) * HD + 32 + quad * 8);

    // staging: granule g = tid (+256): K row = g>>3 (kv), col (g&7)*8 (d)
    //                                  V row = g>>3 (d),  col (g&7)*8 (kv)
    const int srow0 = tid >> 3, scol = (tid & 7) * 8;
    const int lds_off0 = srow0 * FA_PAD + scol;
    const int lds_off1 = (srow0 + 32) * FA_PAD + scol;

    f32x4 o[4];
    #pragma unroll
    for (int i = 0; i < 4; i++) o[i] = (f32x4){0.f, 0.f, 0.f, 0.f};
    f32x4 m_i = (f32x4){-1e30f, -1e30f, -1e30f, -1e30f};
    f32x4 l_i = (f32x4){0.f, 0.f, 0.f, 0.f};

    // prefetch tile 0 into registers
    bf16x8 sK0 = *(const bf16x8*)(Kb + (size_t)srow0 * HD + scol);
    bf16x8 sK1 = *(const bf16x8*)(Kb + (size_t)(srow0 + 32) * HD + scol);
    bf16x8 sV0 = *(const bf16x8*)(Vb + (size_t)srow0 * SEQ + scol);
    bf16x8 sV1 = *(const bf16x8*)(Vb + (size_t)(srow0 + 32) * SEQ + scol);

    for (int kt = 0; kt <= qt; ++kt) {
        const int k0 = kt * 64;
        __syncthreads();                         // prev readers done
        *(bf16x8*)&Ks[lds_off0] = sK0;
        *(bf16x8*)&Ks[lds_off1] = sK1;
        *(bf16x8*)&Vs[lds_off0] = sV0;
        *(bf16x8*)&Vs[lds_off1] = sV1;
        __syncthreads();                         // tile visible

        // prefetch next tile (overlaps the whole compute phase)
        bf16x8 nK0, nK1, nV0, nV1;
        if (kt < qt) {
            const int kn = k0 + 64;
            nK0 = *(const bf16x8*)(Kb + (size_t)(kn + srow0) * HD + scol);
            nK1 = *(const bf16x8*)(Kb + (size_t)(kn + srow0 + 32) * HD + scol);
            nV0 = *(const bf16x8*)(Vb + (size_t)srow0 * SEQ + kn + scol);
            nV1 = *(const bf16x8*)(Vb + (size_t)(srow0 + 32) * SEQ + kn + scol);
        }

        f32x4 sc[4];
        #pragma unroll
        for (int ni = 0; ni < 4; ni++) {
            bf16x8 kb0 = *(const bf16x8*)&Ks[(ni * 16 + l16) * FA_PAD + quad * 8];
            bf16x8 kb1 = *(const bf16x8*)&Ks[(ni * 16 + l16) * FA_PAD + 32 + quad * 8];
            f32x4 t = (f32x4){0.f, 0.f, 0.f, 0.f};
            t = __builtin_amdgcn_mfma_f32_16x16x32_bf16(aq0, kb0, t, 0, 0, 0);
            t = __builtin_amdgcn_mfma_f32_16x16x32_bf16(aq1, kb1, t, 0, 0, 0);
            sc[ni] = t * 0.125f;  // HEAD_DIM^-0.5
        }

        if (kt == qt) {  // diagonal tile: causal mask
            #pragma unroll
            for (int ni = 0; ni < 4; ni++) {
                const int kj = k0 + ni * 16 + l16;
                #pragma unroll
                for (int r = 0; r < 4; r++)
                    if (kj > q0 + quad * 4 + r) sc[ni][r] = -1e30f;
            }
        }

        // row max across the 16 lanes sharing each Q row
        f32x4 vm;
        #pragma unroll
        for (int r = 0; r < 4; r++)
            vm[r] = fmaxf(fmaxf(sc[0][r], sc[1][r]), fmaxf(sc[2][r], sc[3][r]));
        #pragma unroll
        for (int d = 1; d < 16; d <<= 1) {
            #pragma unroll
            for (int r = 0; r < 4; r++)
                vm[r] = fmaxf(vm[r], __shfl_xor(vm[r], d));
        }

        f32x4 mnew, alpha;
        #pragma unroll
        for (int r = 0; r < 4; r++) {
            mnew[r]  = fmaxf(m_i[r], vm[r]);
            alpha[r] = __expf(m_i[r] - mnew[r]);
        }

        f32x4 rs = (f32x4){0.f, 0.f, 0.f, 0.f};
        #pragma unroll
        for (int ni = 0; ni < 4; ni++) {
            #pragma unroll
            for (int r = 0; r < 4; r++) {
                float pv = __expf(sc[ni][r] - mnew[r]);
                rs[r] += pv;
                p_lds[w][quad * 4 + r][ni * 16 + l16] = (bf16_t)pv;  // C-layout -> LDS
            }
        }
        #pragma unroll
        for (int d = 1; d < 16; d <<= 1) {
            #pragma unroll
            for (int r = 0; r < 4; r++)
                rs[r] += __shfl_xor(rs[r], d);
        }

        #pragma unroll
        for (int r = 0; r < 4; r++) l_i[r] = l_i[r] * alpha[r] + rs[r];
        m_i = mnew;
        #pragma unroll
        for (int ni = 0; ni < 4; ni++) o[ni] = o[ni] * alpha;

        // PV: P back in A-layout (wave-private LDS region, no barrier needed)
        #pragma unroll
        for (int ks = 0; ks < 2; ks++) {
            bf16x8 ap = *(const bf16x8*)&p_lds[w][l16][ks * 32 + quad * 8];
            #pragma unroll
            for (int ni = 0; ni < 4; ni++) {
                bf16x8 vb = *(const bf16x8*)&Vs[(ni * 16 + l16) * FA_PAD + ks * 32 + quad * 8];
                o[ni] = __builtin_amdgcn_mfma_f32_16x16x32_bf16(ap, vb, o[ni], 0, 0, 0);
            }
        }

        sK0 = nK0; sK1 = nK1; sV0 = nV0; sV1 = nV1;
    }

    const int b = bh >> 4, h = bh & 15;
    #pragma unroll
    for (int ni = 0; ni < 4; ni++) {
        #pragma unroll
        for (int r = 0; r < 4; r++) {
            const size_t row = (size_t)b * SEQ + q0 + quad * 4 + r;
            AO[row * D_MODEL + h * HD + ni * 16 + l16] = (bf16_t)(o[ni][r] / l_i[r]);
        }
    }
}

// ---------------- launcher ----------------
extern "C" void kernel_launch(void* const* d_in, const int* in_sizes, int n_in,
                              void* d_out, int out_size, void* d_ws, size_t ws_size,
                              hipStream_t stream) {
    const float* x     = (const float*)d_in[0];
    const float* w_qkv = (const float*)d_in[1];
    const float* w_o   = (const float*)d_in[2];
    const int*   tpos  = (const int*)d_in[3];
    float*       out   = (float*)d_out;

    char* ws = (char*)d_ws;
    bf16_t* xb  = (bf16_t*)(ws);                 //  8 MB: x bf16        [4096,1024]
    bf16_t* wqb = (bf16_t*)(ws + 8388608);       //  6 MB: w_qkv bf16    [3072,1024]
    bf16_t* wob = (bf16_t*)(ws + 14680064);      //  2 MB: w_o bf16      [1024,1024]
    bf16_t* qkv = (bf16_t*)(ws + 16777216);      // 24 MB: qkv           [4096,3072]
    bf16_t* Qh  = (bf16_t*)(ws + 41943040);      //  8 MB: Q heads rope  [32,2048,64]
    bf16_t* Kh  = (bf16_t*)(ws + 50331648);      //  8 MB: K heads rope  [32,2048,64]
    bf16_t* VT  = (bf16_t*)(ws + 58720256);      //  8 MB: V^T           [32,64,2048]
    bf16_t* AO  = (bf16_t*)(ws + 67108864);      //  8 MB: attn out      [4096,1024]

    const int nx = MROWS * D_MODEL;      // 4,194,304
    const int nq = QKVN * D_MODEL;       // 3,145,728
    const int no = D_MODEL * D_MODEL;    // 1,048,576

    cvt_f32_bf16<<<nx / 1024, 256, 0, stream>>>(x, xb, nx);
    cvt_f32_bf16<<<nq / 1024, 256, 0, stream>>>(w_qkv, wqb, nq);
    cvt_f32_bf16<<<no / 1024, 256, 0, stream>>>(w_o, wob, no);

    // qkv = x @ w_qkv^T : M=4096, N=3072, K=1024
    gemm_nt<bf16_t><<<dim3(32, 24), 256, 0, stream>>>(xb, wqb, qkv, MROWS, QKVN, D_MODEL);

    rope_split<<<dim3(SEQ / 128, BATCH * NH), 256, 0, stream>>>(qkv, tpos, Qh, Kh, VT);

    flash_attn<<<1024, 256, 0, stream>>>(Qh, Kh, VT, AO);

    // out = AO @ w_o^T : M=4096, N=1024, K=1024 (fp32 out)
    gemm_nt<float><<<dim3(32, 8), 256, 0, stream>>>(AO, wob, out, MROWS, D_MODEL, D_MODEL);
}

// Round 3
// 220.987 us; speedup vs baseline: 2.2967x; 1.1300x over previous
//
#include <hip/hip_runtime.h>
#include <hip/hip_bf16.h>
#include <math.h>

typedef __bf16 bf16_t;
typedef __bf16 bf16x8 __attribute__((ext_vector_type(8)));
typedef __bf16 bf16x4 __attribute__((ext_vector_type(4)));
typedef float  f32x4  __attribute__((ext_vector_type(4)));

#define D_MODEL 1024
#define NH      16
#define HD      64
#define BATCH   2
#define SEQ     2048
#define MROWS   (BATCH*SEQ)   // 4096
#define QKVN    (3*D_MODEL)   // 3072
#define FA_PAD  72            // LDS row stride: 36 dwords -> b128 frag reads conflict-free
#define SCALE_LOG2E 0.18033688011112042f   // 0.125 * log2(e)

__device__ __forceinline__ void async_cp16(const bf16_t* g, bf16_t* l) {
    __builtin_amdgcn_global_load_lds(
        (const __attribute__((address_space(1))) void*)g,
        (__attribute__((address_space(3))) void*)l,
        16, 0, 0);
}

// ---------------- fp32 -> bf16 convert, all three inputs in one launch ------
__global__ void cvt_all(const float* __restrict__ x, const float* __restrict__ wq,
                        const float* __restrict__ wo,
                        bf16_t* __restrict__ xb, bf16_t* __restrict__ wqb,
                        bf16_t* __restrict__ wob) {
    const int nx = MROWS * D_MODEL, nq = QKVN * D_MODEL;
    int i = (blockIdx.x * blockDim.x + threadIdx.x) * 4;
    const float* s; bf16_t* d; int off;
    if (i < nx)           { s = x;  d = xb;  off = i; }
    else if (i < nx + nq) { s = wq; d = wqb; off = i - nx; }
    else                  { s = wo; d = wob; off = i - nx - nq; }
    float4 v = *(const float4*)(s + off);
    d[off]     = (bf16_t)v.x;
    d[off + 1] = (bf16_t)v.y;
    d[off + 2] = (bf16_t)v.z;
    d[off + 3] = (bf16_t)v.w;
}

// ---------------- NT GEMM (m97 recipe): C[M,N] = A[M,K] * B[N,K]^T ----------
// Block tile 128 x (NI*32); wave tile 64 x (NI*16). NI=4 -> 128x128, NI=2 -> 128x64.
template <typename OutT, int NI>
__global__ __launch_bounds__(256) void gemm_nt(const bf16_t* __restrict__ A,
                                               const bf16_t* __restrict__ Bm,
                                               OutT* __restrict__ C,
                                               int M, int N, int K) {
    __shared__ __align__(16) bf16_t As[128 * 32];
    __shared__ __align__(16) bf16_t Bs[NI * 32 * 32];
    const int tid  = threadIdx.x;
    const int w    = tid >> 6;
    const int lane = tid & 63;
    const int quad = lane >> 4;
    const int l16  = lane & 15;
    const int m0   = blockIdx.x * 128;
    const int n0   = blockIdx.y * (NI * 32);
    const int wm   = (w >> 1) * 64;
    const int wn   = (w & 1) * (NI * 16);

    f32x4 acc[4][NI];
    #pragma unroll
    for (int i = 0; i < 4; i++)
        #pragma unroll
        for (int j = 0; j < NI; j++)
            acc[i][j] = (f32x4){0.f, 0.f, 0.f, 0.f};

    const bf16_t* Ag0 = A  + (size_t)(m0 + (tid >> 2)) * K + (tid & 3) * 8;
    const bf16_t* Ag1 = Ag0 + (size_t)64 * K;
    const bf16_t* Bg0 = Bm + (size_t)(n0 + (tid >> 2)) * K + (tid & 3) * 8;
    const bf16_t* Bg1 = Bg0 + (size_t)64 * K;
    bf16_t* Al0 = &As[(size_t)tid * 8];
    bf16_t* Al1 = &As[((size_t)tid + 256) * 8];
    bf16_t* Bl0 = &Bs[(size_t)tid * 8];
    bf16_t* Bl1 = &Bs[((size_t)tid + 256) * 8];

    for (int k0 = 0; k0 < K; k0 += 32) {
        async_cp16(Ag0 + k0, Al0);
        async_cp16(Ag1 + k0, Al1);
        async_cp16(Bg0 + k0, Bl0);
        if (NI == 4) async_cp16(Bg1 + k0, Bl1);
        __syncthreads();

        bf16x8 af[4], bfr[NI];
        #pragma unroll
        for (int mi = 0; mi < 4; mi++)
            af[mi] = *(const bf16x8*)&As[(wm + mi * 16 + l16) * 32 + quad * 8];
        #pragma unroll
        for (int ni = 0; ni < NI; ni++)
            bfr[ni] = *(const bf16x8*)&Bs[(wn + ni * 16 + l16) * 32 + quad * 8];
        #pragma unroll
        for (int mi = 0; mi < 4; mi++)
            #pragma unroll
            for (int ni = 0; ni < NI; ni++)
                acc[mi][ni] = __builtin_amdgcn_mfma_f32_16x16x32_bf16(
                    af[mi], bfr[ni], acc[mi][ni], 0, 0, 0);
        __syncthreads();
    }

    #pragma unroll
    for (int mi = 0; mi < 4; mi++)
        #pragma unroll
        for (int ni = 0; ni < NI; ni++) {
            const int col = n0 + wn + ni * 16 + l16;
            #pragma unroll
            for (int r = 0; r < 4; r++) {
                const int row = m0 + wm + mi * 16 + quad * 4 + r;
                C[(size_t)row * N + col] = (OutT)acc[mi][ni][r];
            }
        }
}

// ---------------- RoPE + head split + V transpose (coalesced) ----------------
__global__ __launch_bounds__(256) void rope_split(const bf16_t* __restrict__ qkv,
                                                  const int* __restrict__ pos,
                                                  bf16_t* __restrict__ Qh,
                                                  bf16_t* __restrict__ Kh,
                                                  bf16_t* __restrict__ VT) {
    __shared__ bf16_t vs[128][FA_PAD];
    const int tid   = threadIdx.x;
    const int s_loc = tid >> 1;
    const int half  = tid & 1;
    const int s0    = blockIdx.x * 128;
    const int bh    = blockIdx.y;
    const int b     = bh >> 4, h = bh & 15;
    const int s     = s0 + s_loc;

    const bf16_t* row = qkv + (size_t)(b * SEQ + s) * QKVN + h * HD + half * 32;

    bf16_t qbuf[32], kbuf[32], vbuf[32];
    #pragma unroll
    for (int j = 0; j < 4; j++) {
        *(bf16x8*)&qbuf[j * 8] = *(const bf16x8*)(row + j * 8);
        *(bf16x8*)&kbuf[j * 8] = *(const bf16x8*)(row + D_MODEL + j * 8);
        *(bf16x8*)&vbuf[j * 8] = *(const bf16x8*)(row + 2 * D_MODEL + j * 8);
    }

    const float pf = (float)pos[s];
    #pragma unroll
    for (int p = 0; p < 16; p++) {
        const int d2 = half * 16 + p;
        const float inv = __expf(-0.28782313662425575f * (float)d2);
        const float f = pf * inv;
        const float c = cosf(f), sn = sinf(f);
        float qe = (float)qbuf[2 * p], qo = (float)qbuf[2 * p + 1];
        float ke = (float)kbuf[2 * p], ko = (float)kbuf[2 * p + 1];
        qbuf[2 * p]     = (bf16_t)(qe * c - qo * sn);
        qbuf[2 * p + 1] = (bf16_t)(qo * c + qe * sn);
        kbuf[2 * p]     = (bf16_t)(ke * c - ko * sn);
        kbuf[2 * p + 1] = (bf16_t)(ko * c + ke * sn);
    }

    bf16_t* qdst = Qh + ((size_t)bh * SEQ + s) * HD + half * 32;
    bf16_t* kdst = Kh + ((size_t)bh * SEQ + s) * HD + half * 32;
    #pragma unroll
    for (int j = 0; j < 4; j++) {
        *(bf16x8*)(qdst + j * 8) = *(bf16x8*)&qbuf[j * 8];
        *(bf16x8*)(kdst + j * 8) = *(bf16x8*)&kbuf[j * 8];
        *(bf16x8*)&vs[s_loc][half * 32 + j * 8] = *(bf16x8*)&vbuf[j * 8];
    }
    __syncthreads();

    const int d  = tid >> 2;
    const int sc = tid & 3;
    bf16_t tmp[32];
    #pragma unroll
    for (int i = 0; i < 32; i++) tmp[i] = vs[sc * 32 + i][d];
    bf16_t* vdst = VT + ((size_t)bh * HD + d) * SEQ + s0 + sc * 32;
    #pragma unroll
    for (int j = 0; j < 4; j++)
        *(bf16x8*)(vdst + j * 8) = *(bf16x8*)&tmp[j * 8];
}

// ---------------- causal flash attention, max-free softmax ------------------
// S^T = K*Q^T trick: C-layout row = kv, col = q -> each lane holds 4 consecutive
// kv for one q; P^T stored with b64 writes, read back as contiguous A-frags.
// No max tracking / no alpha rescale / no per-iter reduction trees.
__global__ __launch_bounds__(256) void flash_attn(const bf16_t* __restrict__ Qh,
                                                  const bf16_t* __restrict__ Kh,
                                                  const bf16_t* __restrict__ VT,
                                                  bf16_t* __restrict__ AO) {
    __shared__ __align__(16) bf16_t Ks[64 * FA_PAD];       // [kv][d]
    __shared__ __align__(16) bf16_t Vs[64 * FA_PAD];       // [d][kv]
    __shared__ __align__(16) bf16_t pT[4][16][FA_PAD];     // per-wave: [q][kv]

    const int tid  = threadIdx.x;
    const int w    = tid >> 6;
    const int lane = tid & 63;
    const int quad = lane >> 4;
    const int l16  = lane & 15;

    const int bid = blockIdx.x;
    const int xcd = bid & 7;
    const int mm  = bid >> 3;
    const int bh  = (mm >> 5) * 8 + xcd;      // same-bh blocks share an XCD
    const int qt  = 31 - (mm & 31);           // big q-tiles dispatch first

    const bf16_t* Qb = Qh + (size_t)bh * SEQ * HD;
    const bf16_t* Kb = Kh + (size_t)bh * SEQ * HD;
    const bf16_t* Vb = VT + (size_t)bh * HD * SEQ;

    const int q0 = qt * 64 + w * 16;
    const bf16x8 aq0 = *(const bf16x8*)(Qb + (size_t)(q0 + l16) * HD + quad * 8);
    const bf16x8 aq1 = *(const bf16x8*)(Qb + (size_t)(q0 + l16) * HD + 32 + quad * 8);

    const int srow0 = tid >> 3, scol = (tid & 7) * 8;
    const int lds_off0 = srow0 * FA_PAD + scol;
    const int lds_off1 = (srow0 + 32) * FA_PAD + scol;

    f32x4 o[4];
    #pragma unroll
    for (int i = 0; i < 4; i++) o[i] = (f32x4){0.f, 0.f, 0.f, 0.f};
    float lsum = 0.f;

    // prefetch tile 0 into registers
    bf16x8 sK0 = *(const bf16x8*)(Kb + (size_t)srow0 * HD + scol);
    bf16x8 sK1 = *(const bf16x8*)(Kb + (size_t)(srow0 + 32) * HD + scol);
    bf16x8 sV0 = *(const bf16x8*)(Vb + (size_t)srow0 * SEQ + scol);
    bf16x8 sV1 = *(const bf16x8*)(Vb + (size_t)(srow0 + 32) * SEQ + scol);

    for (int kt = 0; kt <= qt; ++kt) {
        const int k0 = kt * 64;
        __syncthreads();
        *(bf16x8*)&Ks[lds_off0] = sK0;
        *(bf16x8*)&Ks[lds_off1] = sK1;
        *(bf16x8*)&Vs[lds_off0] = sV0;
        *(bf16x8*)&Vs[lds_off1] = sV1;
        __syncthreads();

        // prefetch next tile (overlaps compute)
        bf16x8 nK0, nK1, nV0, nV1;
        if (kt < qt) {
            const int kn = k0 + 64;
            nK0 = *(const bf16x8*)(Kb + (size_t)(kn + srow0) * HD + scol);
            nK1 = *(const bf16x8*)(Kb + (size_t)(kn + srow0 + 32) * HD + scol);
            nV0 = *(const bf16x8*)(Vb + (size_t)srow0 * SEQ + kn + scol);
            nV1 = *(const bf16x8*)(Vb + (size_t)(srow0 + 32) * SEQ + kn + scol);
        }

        const bool diag = (kt == qt);
        #pragma unroll
        for (int ni = 0; ni < 4; ni++) {
            if (diag && ni > w) {   // fully-masked kv sub-tile: just zero P
                *(bf16x4*)&pT[w][l16][ni * 16 + quad * 4] = (bf16x4){0, 0, 0, 0};
                continue;
            }
            bf16x8 kb0 = *(const bf16x8*)&Ks[(ni * 16 + l16) * FA_PAD + quad * 8];
            bf16x8 kb1 = *(const bf16x8*)&Ks[(ni * 16 + l16) * FA_PAD + 32 + quad * 8];
            f32x4 t = (f32x4){0.f, 0.f, 0.f, 0.f};
            t = __builtin_amdgcn_mfma_f32_16x16x32_bf16(kb0, aq0, t, 0, 0, 0);  // S^T
            t = __builtin_amdgcn_mfma_f32_16x16x32_bf16(kb1, aq1, t, 0, 0, 0);
            bf16x4 pk;
            #pragma unroll
            for (int r = 0; r < 4; r++) {
                float pv = exp2f(t[r] * SCALE_LOG2E);
                if (diag && (ni * 16 + quad * 4 + r > w * 16 + l16)) pv = 0.f;  // kv > q
                lsum += pv;
                pk[r] = (bf16_t)pv;
            }
            *(bf16x4*)&pT[w][l16][ni * 16 + quad * 4] = pk;
        }

        // PV: P is wave-private -> no barrier
        #pragma unroll
        for (int ks = 0; ks < 2; ks++) {
            if (diag && w * 16 + 15 < ks * 32) continue;  // P block all zero
            bf16x8 ap = *(const bf16x8*)&pT[w][l16][ks * 32 + quad * 8];
            #pragma unroll
            for (int ni = 0; ni < 4; ni++) {
                bf16x8 vb = *(const bf16x8*)&Vs[(ni * 16 + l16) * FA_PAD + ks * 32 + quad * 8];
                o[ni] = __builtin_amdgcn_mfma_f32_16x16x32_bf16(ap, vb, o[ni], 0, 0, 0);
            }
        }

        sK0 = nK0; sK1 = nK1; sV0 = nV0; sV1 = nV1;
    }

    // finalize row sums: reduce over the 4 quads, then redistribute to C-layout rows
    lsum += __shfl_xor(lsum, 16);
    lsum += __shfl_xor(lsum, 32);
    f32x4 linv;
    #pragma unroll
    for (int r = 0; r < 4; r++)
        linv[r] = 1.0f / __shfl(lsum, quad * 4 + r);  // lane q holds sum for q-row q

    const int b = bh >> 4, h = bh & 15;
    #pragma unroll
    for (int ni = 0; ni < 4; ni++) {
        #pragma unroll
        for (int r = 0; r < 4; r++) {
            const size_t row = (size_t)b * SEQ + q0 + quad * 4 + r;
            AO[row * D_MODEL + h * HD + ni * 16 + l16] = (bf16_t)(o[ni][r] * linv[r]);
        }
    }
}

// ---------------- launcher ----------------
extern "C" void kernel_launch(void* const* d_in, const int* in_sizes, int n_in,
                              void* d_out, int out_size, void* d_ws, size_t ws_size,
                              hipStream_t stream) {
    const float* x     = (const float*)d_in[0];
    const float* w_qkv = (const float*)d_in[1];
    const float* w_o   = (const float*)d_in[2];
    const int*   tpos  = (const int*)d_in[3];
    float*       out   = (float*)d_out;

    char* ws = (char*)d_ws;
    bf16_t* xb  = (bf16_t*)(ws);                 //  8 MB
    bf16_t* wqb = (bf16_t*)(ws + 8388608);       //  6 MB
    bf16_t* wob = (bf16_t*)(ws + 14680064);      //  2 MB
    bf16_t* qkv = (bf16_t*)(ws + 16777216);      // 24 MB
    bf16_t* Qh  = (bf16_t*)(ws + 41943040);      //  8 MB
    bf16_t* Kh  = (bf16_t*)(ws + 50331648);      //  8 MB
    bf16_t* VT  = (bf16_t*)(ws + 58720256);      //  8 MB
    bf16_t* AO  = (bf16_t*)(ws + 67108864);      //  8 MB

    cvt_all<<<8192, 256, 0, stream>>>(x, w_qkv, w_o, xb, wqb, wob);

    // qkv = x @ w_qkv^T : M=4096, N=3072, K=1024
    gemm_nt<bf16_t, 4><<<dim3(32, 24), 256, 0, stream>>>(xb, wqb, qkv, MROWS, QKVN, D_MODEL);

    rope_split<<<dim3(SEQ / 128, BATCH * NH), 256, 0, stream>>>(qkv, tpos, Qh, Kh, VT);

    flash_attn<<<1024, 256, 0, stream>>>(Qh, Kh, VT, AO);

    // out = AO @ w_o^T : M=4096, N=1024, K=1024 (fp32 out), 128x64 tiles -> 512 blocks
    gemm_nt<float, 2><<<dim3(32, 16), 256, 0, stream>>>(AO, wob, out, MROWS, D_MODEL, D_MODEL);
}

// Round 4
// 201.644 us; speedup vs baseline: 2.5170x; 1.0959x over previous
//
#include <hip/hip_runtime.h>
#include <hip/hip_bf16.h>
#include <math.h>

typedef __bf16 bf16_t;
typedef __bf16 bf16x8 __attribute__((ext_vector_type(8)));
typedef __bf16 bf16x4 __attribute__((ext_vector_type(4)));
typedef float  f32x4  __attribute__((ext_vector_type(4)));

#define D_MODEL 1024
#define NH      16
#define HD      64
#define BATCH   2
#define SEQ     2048
#define MROWS   (BATCH*SEQ)   // 4096
#define QKVN    (3*D_MODEL)   // 3072
#define FA_PAD  72            // LDS row stride: frag b128 reads at wave64 structural min
#define SCALE_LOG2E 0.18033688011112042f   // 0.125 * log2(e)

__device__ __forceinline__ void async_cp16(const bf16_t* g, bf16_t* l) {
    __builtin_amdgcn_global_load_lds(
        (const __attribute__((address_space(1))) void*)g,
        (__attribute__((address_space(3))) void*)l,
        16, 0, 0);
}

// ---------------- fp32 -> bf16 convert, all three inputs in one launch ------
__global__ void cvt_all(const float* __restrict__ x, const float* __restrict__ wq,
                        const float* __restrict__ wo,
                        bf16_t* __restrict__ xb, bf16_t* __restrict__ wqb,
                        bf16_t* __restrict__ wob) {
    const int nx = MROWS * D_MODEL, nq = QKVN * D_MODEL;
    int i = (blockIdx.x * blockDim.x + threadIdx.x) * 4;
    const float* s; bf16_t* d; int off;
    if (i < nx)           { s = x;  d = xb;  off = i; }
    else if (i < nx + nq) { s = wq; d = wqb; off = i - nx; }
    else                  { s = wo; d = wob; off = i - nx - nq; }
    float4 v = *(const float4*)(s + off);
    d[off]     = (bf16_t)v.x;
    d[off + 1] = (bf16_t)v.y;
    d[off + 2] = (bf16_t)v.z;
    d[off + 3] = (bf16_t)v.w;
}

// ---------------- NT GEMM (m97 recipe): C[M,N] = A[M,K] * B[N,K]^T ----------
template <typename OutT, int NI>
__global__ __launch_bounds__(256) void gemm_nt(const bf16_t* __restrict__ A,
                                               const bf16_t* __restrict__ Bm,
                                               OutT* __restrict__ C,
                                               int M, int N, int K) {
    __shared__ __align__(16) bf16_t As[128 * 32];
    __shared__ __align__(16) bf16_t Bs[NI * 32 * 32];
    const int tid  = threadIdx.x;
    const int w    = tid >> 6;
    const int lane = tid & 63;
    const int quad = lane >> 4;
    const int l16  = lane & 15;
    const int m0   = blockIdx.x * 128;
    const int n0   = blockIdx.y * (NI * 32);
    const int wm   = (w >> 1) * 64;
    const int wn   = (w & 1) * (NI * 16);

    f32x4 acc[4][NI];
    #pragma unroll
    for (int i = 0; i < 4; i++)
        #pragma unroll
        for (int j = 0; j < NI; j++)
            acc[i][j] = (f32x4){0.f, 0.f, 0.f, 0.f};

    const bf16_t* Ag0 = A  + (size_t)(m0 + (tid >> 2)) * K + (tid & 3) * 8;
    const bf16_t* Ag1 = Ag0 + (size_t)64 * K;
    const bf16_t* Bg0 = Bm + (size_t)(n0 + (tid >> 2)) * K + (tid & 3) * 8;
    const bf16_t* Bg1 = Bg0 + (size_t)64 * K;
    bf16_t* Al0 = &As[(size_t)tid * 8];
    bf16_t* Al1 = &As[((size_t)tid + 256) * 8];
    bf16_t* Bl0 = &Bs[(size_t)tid * 8];
    bf16_t* Bl1 = &Bs[((size_t)tid + 256) * 8];

    for (int k0 = 0; k0 < K; k0 += 32) {
        async_cp16(Ag0 + k0, Al0);
        async_cp16(Ag1 + k0, Al1);
        async_cp16(Bg0 + k0, Bl0);
        if (NI == 4) async_cp16(Bg1 + k0, Bl1);
        __syncthreads();

        bf16x8 af[4], bfr[NI];
        #pragma unroll
        for (int mi = 0; mi < 4; mi++)
            af[mi] = *(const bf16x8*)&As[(wm + mi * 16 + l16) * 32 + quad * 8];
        #pragma unroll
        for (int ni = 0; ni < NI; ni++)
            bfr[ni] = *(const bf16x8*)&Bs[(wn + ni * 16 + l16) * 32 + quad * 8];
        #pragma unroll
        for (int mi = 0; mi < 4; mi++)
            #pragma unroll
            for (int ni = 0; ni < NI; ni++)
                acc[mi][ni] = __builtin_amdgcn_mfma_f32_16x16x32_bf16(
                    af[mi], bfr[ni], acc[mi][ni], 0, 0, 0);
        __syncthreads();
    }

    #pragma unroll
    for (int mi = 0; mi < 4; mi++)
        #pragma unroll
        for (int ni = 0; ni < NI; ni++) {
            const int col = n0 + wn + ni * 16 + l16;
            #pragma unroll
            for (int r = 0; r < 4; r++) {
                const int row = m0 + wm + mi * 16 + quad * 4 + r;
                C[(size_t)row * N + col] = (OutT)acc[mi][ni][r];
            }
        }
}

// ---------------- RoPE + head split + V transpose (coalesced) ----------------
__global__ __launch_bounds__(256) void rope_split(const bf16_t* __restrict__ qkv,
                                                  const int* __restrict__ pos,
                                                  bf16_t* __restrict__ Qh,
                                                  bf16_t* __restrict__ Kh,
                                                  bf16_t* __restrict__ VT) {
    __shared__ bf16_t vs[128][FA_PAD];
    const int tid   = threadIdx.x;
    const int s_loc = tid >> 1;
    const int half  = tid & 1;
    const int s0    = blockIdx.x * 128;
    const int bh    = blockIdx.y;
    const int b     = bh >> 4, h = bh & 15;
    const int s     = s0 + s_loc;

    const bf16_t* row = qkv + (size_t)(b * SEQ + s) * QKVN + h * HD + half * 32;

    bf16_t qbuf[32], kbuf[32], vbuf[32];
    #pragma unroll
    for (int j = 0; j < 4; j++) {
        *(bf16x8*)&qbuf[j * 8] = *(const bf16x8*)(row + j * 8);
        *(bf16x8*)&kbuf[j * 8] = *(const bf16x8*)(row + D_MODEL + j * 8);
        *(bf16x8*)&vbuf[j * 8] = *(const bf16x8*)(row + 2 * D_MODEL + j * 8);
    }

    const float pf = (float)pos[s];
    #pragma unroll
    for (int p = 0; p < 16; p++) {
        const int d2 = half * 16 + p;
        const float inv = __expf(-0.28782313662425575f * (float)d2);
        const float f = pf * inv;
        const float c = cosf(f), sn = sinf(f);
        float qe = (float)qbuf[2 * p], qo = (float)qbuf[2 * p + 1];
        float ke = (float)kbuf[2 * p], ko = (float)kbuf[2 * p + 1];
        qbuf[2 * p]     = (bf16_t)(qe * c - qo * sn);
        qbuf[2 * p + 1] = (bf16_t)(qo * c + qe * sn);
        kbuf[2 * p]     = (bf16_t)(ke * c - ko * sn);
        kbuf[2 * p + 1] = (bf16_t)(ko * c + ke * sn);
    }

    bf16_t* qdst = Qh + ((size_t)bh * SEQ + s) * HD + half * 32;
    bf16_t* kdst = Kh + ((size_t)bh * SEQ + s) * HD + half * 32;
    #pragma unroll
    for (int j = 0; j < 4; j++) {
        *(bf16x8*)(qdst + j * 8) = *(bf16x8*)&qbuf[j * 8];
        *(bf16x8*)(kdst + j * 8) = *(bf16x8*)&kbuf[j * 8];
        *(bf16x8*)&vs[s_loc][half * 32 + j * 8] = *(bf16x8*)&vbuf[j * 8];
    }
    __syncthreads();

    const int d  = tid >> 2;
    const int sc = tid & 3;
    bf16_t tmp[32];
    #pragma unroll
    for (int i = 0; i < 32; i++) tmp[i] = vs[sc * 32 + i][d];
    bf16_t* vdst = VT + ((size_t)bh * HD + d) * SEQ + s0 + sc * 32;
    #pragma unroll
    for (int j = 0; j < 4; j++)
        *(bf16x8*)(vdst + j * 8) = *(bf16x8*)&tmp[j * 8];
}

// ---------------- causal flash attention: folded pairs, 8 waves, dbuf LDS ---
// Block = 512 thr = 8 waves: waves 0-3 -> q-tile (31-pair), waves 4-7 -> q-tile
// pair. Both share one staged K/V tile; total active wave-iters = 132 per block
// (perfectly balanced). Double-buffered K/V, ONE barrier per iter. Max-free
// softmax via S^T = K*Q^T (P lands transposed -> contiguous A-frag reads).
__global__ __launch_bounds__(512) void flash_attn(const bf16_t* __restrict__ Qh,
                                                  const bf16_t* __restrict__ Kh,
                                                  const bf16_t* __restrict__ VT,
                                                  bf16_t* __restrict__ AO) {
    __shared__ __align__(16) bf16_t Ks[2][64 * FA_PAD];    // [buf][kv][d]
    __shared__ __align__(16) bf16_t Vs[2][64 * FA_PAD];    // [buf][d][kv]
    __shared__ __align__(16) bf16_t pT[8][16][FA_PAD];     // per-wave: [q][kv]

    const int tid  = threadIdx.x;
    const int w    = tid >> 6;
    const int lane = tid & 63;
    const int quad = lane >> 4;
    const int l16  = lane & 15;
    const int wq   = w & 3;        // wave's 16-row slice within its q-tile
    const int g    = w >> 2;       // 0 = big tile, 1 = small tile

    const int bid  = blockIdx.x;
    const int xcd  = bid & 7;
    const int mm   = bid >> 3;                 // 0..63
    const int bh   = (mm >> 4) * 8 + xcd;      // same-bh blocks share an XCD
    const int pair = mm & 15;                  // pair 0 (longest) dispatches first
    const int qt_big = 31 - pair;
    const int my_qt  = g ? pair : qt_big;
    const int niter  = qt_big + 1;             // 17..32

    const bf16_t* Qb = Qh + (size_t)bh * SEQ * HD;
    const bf16_t* Kb = Kh + (size_t)bh * SEQ * HD;
    const bf16_t* Vb = VT + (size_t)bh * HD * SEQ;

    const int q0 = my_qt * 64 + wq * 16;
    const bf16x8 aq0 = *(const bf16x8*)(Qb + (size_t)(q0 + l16) * HD + quad * 8);
    const bf16x8 aq1 = *(const bf16x8*)(Qb + (size_t)(q0 + l16) * HD + 32 + quad * 8);

    // staging: 512 threads, one b128 each for K and V: row = tid>>3, col = (tid&7)*8
    const int srow = tid >> 3, scol = (tid & 7) * 8;
    const int lds_off = srow * FA_PAD + scol;

    f32x4 o[4];
    #pragma unroll
    for (int i = 0; i < 4; i++) o[i] = (f32x4){0.f, 0.f, 0.f, 0.f};
    float lsum = 0.f;

    // prologue: tile 0 -> buf 0
    bf16x8 pK = *(const bf16x8*)(Kb + (size_t)srow * HD + scol);
    bf16x8 pV = *(const bf16x8*)(Vb + (size_t)srow * SEQ + scol);
    *(bf16x8*)&Ks[0][lds_off] = pK;
    *(bf16x8*)&Vs[0][lds_off] = pV;

    for (int kt = 0; kt < niter; ++kt) {
        const int cur = kt & 1;
        // prefetch next tile before the barrier: loads span barrier-wait + compute
        if (kt + 1 < niter) {
            const int kn = (kt + 1) * 64;
            pK = *(const bf16x8*)(Kb + (size_t)(kn + srow) * HD + scol);
            pV = *(const bf16x8*)(Vb + (size_t)srow * SEQ + kn + scol);
        }
        __syncthreads();   // buf[cur] visible; everyone done reading buf[cur^1]

        if (kt <= my_qt) {
            const bool diag = (kt == my_qt);
            const bf16_t* KsC = &Ks[cur][0];
            const bf16_t* VsC = &Vs[cur][0];

            #pragma unroll
            for (int ni = 0; ni < 4; ni++) {
                if (diag && ni > wq) {   // fully-masked kv sub-tile
                    *(bf16x4*)&pT[w][l16][ni * 16 + quad * 4] = (bf16x4){0, 0, 0, 0};
                    continue;
                }
                bf16x8 kb0 = *(const bf16x8*)&KsC[(ni * 16 + l16) * FA_PAD + quad * 8];
                bf16x8 kb1 = *(const bf16x8*)&KsC[(ni * 16 + l16) * FA_PAD + 32 + quad * 8];
                f32x4 t = (f32x4){0.f, 0.f, 0.f, 0.f};
                t = __builtin_amdgcn_mfma_f32_16x16x32_bf16(kb0, aq0, t, 0, 0, 0);  // S^T
                t = __builtin_amdgcn_mfma_f32_16x16x32_bf16(kb1, aq1, t, 0, 0, 0);
                bf16x4 pk;
                #pragma unroll
                for (int r = 0; r < 4; r++) {
                    float pv = exp2f(t[r] * SCALE_LOG2E);
                    if (diag && (ni * 16 + quad * 4 + r > wq * 16 + l16)) pv = 0.f;
                    lsum += pv;
                    pk[r] = (bf16_t)pv;
                }
                *(bf16x4*)&pT[w][l16][ni * 16 + quad * 4] = pk;
            }

            // PV: pT is wave-private -> no barrier
            #pragma unroll
            for (int ks = 0; ks < 2; ks++) {
                if (diag && wq * 16 + 15 < ks * 32) continue;
                bf16x8 ap = *(const bf16x8*)&pT[w][l16][ks * 32 + quad * 8];
                #pragma unroll
                for (int ni = 0; ni < 4; ni++) {
                    bf16x8 vb = *(const bf16x8*)&VsC[(ni * 16 + l16) * FA_PAD + ks * 32 + quad * 8];
                    o[ni] = __builtin_amdgcn_mfma_f32_16x16x32_bf16(ap, vb, o[ni], 0, 0, 0);
                }
            }
        }

        if (kt + 1 < niter) {
            *(bf16x8*)&Ks[cur ^ 1][lds_off] = pK;
            *(bf16x8*)&Vs[cur ^ 1][lds_off] = pV;
        }
    }

    // finalize: reduce lsum over quads, redistribute to C-layout rows
    lsum += __shfl_xor(lsum, 16);
    lsum += __shfl_xor(lsum, 32);
    f32x4 linv;
    #pragma unroll
    for (int r = 0; r < 4; r++)
        linv[r] = 1.0f / __shfl(lsum, quad * 4 + r);

    const int b = bh >> 4, h = bh & 15;
    #pragma unroll
    for (int ni = 0; ni < 4; ni++) {
        #pragma unroll
        for (int r = 0; r < 4; r++) {
            const size_t row = (size_t)b * SEQ + q0 + quad * 4 + r;
            AO[row * D_MODEL + h * HD + ni * 16 + l16] = (bf16_t)(o[ni][r] * linv[r]);
        }
    }
}

// ---------------- launcher ----------------
extern "C" void kernel_launch(void* const* d_in, const int* in_sizes, int n_in,
                              void* d_out, int out_size, void* d_ws, size_t ws_size,
                              hipStream_t stream) {
    const float* x     = (const float*)d_in[0];
    const float* w_qkv = (const float*)d_in[1];
    const float* w_o   = (const float*)d_in[2];
    const int*   tpos  = (const int*)d_in[3];
    float*       out   = (float*)d_out;

    char* ws = (char*)d_ws;
    bf16_t* xb  = (bf16_t*)(ws);                 //  8 MB
    bf16_t* wqb = (bf16_t*)(ws + 8388608);       //  6 MB
    bf16_t* wob = (bf16_t*)(ws + 14680064);      //  2 MB
    bf16_t* qkv = (bf16_t*)(ws + 16777216);      // 24 MB
    bf16_t* Qh  = (bf16_t*)(ws + 41943040);      //  8 MB
    bf16_t* Kh  = (bf16_t*)(ws + 50331648);      //  8 MB
    bf16_t* VT  = (bf16_t*)(ws + 58720256);      //  8 MB
    bf16_t* AO  = (bf16_t*)(ws + 67108864);      //  8 MB

    cvt_all<<<8192, 256, 0, stream>>>(x, w_qkv, w_o, xb, wqb, wob);

    // qkv = x @ w_qkv^T : M=4096, N=3072, K=1024
    gemm_nt<bf16_t, 4><<<dim3(32, 24), 256, 0, stream>>>(xb, wqb, qkv, MROWS, QKVN, D_MODEL);

    rope_split<<<dim3(SEQ / 128, BATCH * NH), 256, 0, stream>>>(qkv, tpos, Qh, Kh, VT);

    flash_attn<<<512, 512, 0, stream>>>(Qh, Kh, VT, AO);

    // out = AO @ w_o^T : M=4096, N=1024, K=1024 (fp32 out)
    gemm_nt<float, 2><<<dim3(32, 16), 256, 0, stream>>>(AO, wob, out, MROWS, D_MODEL, D_MODEL);
}